// Round 1
// baseline (298.932 us; speedup 1.0000x reference)
//
#include <hip/hip_runtime.h>
#include <hip/hip_bf16.h>
#include <cstdint>

typedef short short8 __attribute__((ext_vector_type(8)));
typedef float f32x4 __attribute__((ext_vector_type(4)));

#define MFMA16(a, b, c) __builtin_amdgcn_mfma_f32_16x16x32_bf16((a), (b), (c), 0, 0, 0)

__device__ __forceinline__ float b2f(unsigned short u) {
    unsigned x = ((unsigned)u) << 16;
    return __builtin_bit_cast(float, x);
}
__device__ __forceinline__ unsigned short f2b(float f) {
    unsigned x = __builtin_bit_cast(unsigned, f);
    unsigned r = (x + 0x7fffu + ((x >> 16) & 1u)) >> 16;
    return (unsigned short)r;
}

__device__ __forceinline__ void gl_lds16(const void* g, void* l) {
    __builtin_amdgcn_global_load_lds((const __attribute__((address_space(1))) void*)g,
                                     (__attribute__((address_space(3))) void*)l, 16, 0, 0);
}

// ---------------- RMSNorm: fp32 x -> bf16 xn ----------------
__global__ void rmsnorm_kernel(const float* __restrict__ x, const float* __restrict__ scale,
                               unsigned short* __restrict__ xn) {
    const int row = blockIdx.x;
    const int tid = threadIdx.x;
    const float4* xr = (const float4*)(x + (size_t)row * 1024);
    float4 vx = xr[tid];
    float ss = vx.x * vx.x + vx.y * vx.y + vx.z * vx.z + vx.w * vx.w;
#pragma unroll
    for (int m = 1; m < 64; m <<= 1) ss += __shfl_xor(ss, m);
    __shared__ float wsum[4];
    if ((tid & 63) == 0) wsum[tid >> 6] = ss;
    __syncthreads();
    float tot = wsum[0] + wsum[1] + wsum[2] + wsum[3];
    float rs = rsqrtf(tot * (1.0f / 1024.0f) + 1e-6f);
    const float4* sr = (const float4*)scale;
    float4 sv = sr[tid];
    ushort4 r;
    r.x = f2b(vx.x * sv.x * rs);
    r.y = f2b(vx.y * sv.y * rs);
    r.z = f2b(vx.z * sv.z * rs);
    r.w = f2b(vx.w * sv.w * rs);
    *(ushort4*)(xn + (size_t)row * 1024 + tid * 4) = r;
}

// ---------------- f32 -> bf16 convert ----------------
__global__ void f2b_kernel(const float* __restrict__ in, unsigned short* __restrict__ outp, int n4) {
    int i = blockIdx.x * 256 + threadIdx.x;
    if (i < n4) {
        float4 vv = ((const float4*)in)[i];
        ushort4 r;
        r.x = f2b(vv.x);
        r.y = f2b(vv.y);
        r.z = f2b(vv.z);
        r.w = f2b(vv.w);
        ((ushort4*)outp)[i] = r;
    }
}

// ---------------- GEMM C = A * B^T (A: MxK bf16 row-major, B: NxK bf16 row-major) ----
// EPI 0: scatter qkv -> q,k,v (B,H,S,D) bf16, q scaled by 0.125
// EPI 1: out[m][n] = acc + skip[m][n]  (fp32)
constexpr int BM = 128, BN = 128, BK = 64, KDIM = 1024, NT = KDIM / BK;

template <int EPI>
__launch_bounds__(256, 2) __global__
    void gemm_bt(const unsigned short* __restrict__ A, const unsigned short* __restrict__ Bw,
                 unsigned short* __restrict__ qo, unsigned short* __restrict__ ko,
                 unsigned short* __restrict__ vo, const float* __restrict__ skip,
                 float* __restrict__ out) {
    __shared__ unsigned short As[2][BM * BK];
    __shared__ unsigned short Bs[2][BN * BK];
    const int tid = threadIdx.x;
    const int lane = tid & 63, w = tid >> 6;
    const int wr = w >> 1, wc = w & 1;
    const int lr = lane & 15, lg = lane >> 4;
    const int m0 = blockIdx.y * BM;
    const int n0 = blockIdx.x * BN;
    const int NCOL = (EPI == 0) ? 3072 : 1024;

    f32x4 acc[4][4] = {};

    auto stage = [&](int buf, int kt) {
        const int k0 = kt * BK;
#pragma unroll
        for (int i = 0; i < 4; ++i) {
            int seg = i * 256 + tid;
            int row = seg >> 3, c8 = seg & 7;
            gl_lds16(A + (size_t)(m0 + row) * KDIM + k0 + c8 * 8,
                     &As[buf][(i * 256 + w * 64) * 8]);
            gl_lds16(Bw + (size_t)(n0 + row) * KDIM + k0 + c8 * 8,
                     &Bs[buf][(i * 256 + w * 64) * 8]);
        }
    };

    stage(0, 0);
    __syncthreads();
    int cur = 0;
    for (int kt = 0; kt < NT; ++kt) {
        if (kt + 1 < NT) stage(cur ^ 1, kt + 1);
#pragma unroll
        for (int kkc = 0; kkc < 2; ++kkc) {
            short8 a[4], b[4];
#pragma unroll
            for (int m = 0; m < 4; ++m)
                a[m] = *(const short8*)&As[cur][(wr * 64 + m * 16 + lr) * BK + kkc * 32 + lg * 8];
#pragma unroll
            for (int n = 0; n < 4; ++n)
                b[n] = *(const short8*)&Bs[cur][(wc * 64 + n * 16 + lr) * BK + kkc * 32 + lg * 8];
#pragma unroll
            for (int m = 0; m < 4; ++m)
#pragma unroll
                for (int n = 0; n < 4; ++n) acc[m][n] = MFMA16(a[m], b[n], acc[m][n]);
        }
        __syncthreads();
        cur ^= 1;
    }

    if (EPI == 0) {
#pragma unroll
        for (int m = 0; m < 4; ++m)
#pragma unroll
            for (int n = 0; n < 4; ++n) {
                int gcol = n0 + wc * 64 + n * 16 + lr;
                int c = gcol >> 10, h = (gcol >> 6) & 15, d = gcol & 63;
                unsigned short* dst = (c == 0) ? qo : ((c == 1) ? ko : vo);
                float sc = (c == 0) ? 0.125f : 1.0f;
#pragma unroll
                for (int j = 0; j < 4; ++j) {
                    int grow = m0 + wr * 64 + m * 16 + lg * 4 + j;
                    int b = grow >> 10, s = grow & 1023;
                    dst[(((size_t)(b * 16 + h)) * 1024 + s) * 64 + d] = f2b(acc[m][n][j] * sc);
                }
            }
    } else {
#pragma unroll
        for (int m = 0; m < 4; ++m)
#pragma unroll
            for (int n = 0; n < 4; ++n) {
                int gcol = n0 + wc * 64 + n * 16 + lr;
#pragma unroll
                for (int j = 0; j < 4; ++j) {
                    int grow = m0 + wr * 64 + m * 16 + lg * 4 + j;
                    size_t idx = (size_t)grow * NCOL + gcol;
                    out[idx] = acc[m][n][j] + skip[idx];
                }
            }
    }
}

// ---------------- RoPE (in-place on q and k, bf16, layout (B,H,S,D)) ----------------
__global__ void rope_kernel(unsigned short* __restrict__ q, unsigned short* __restrict__ k,
                            const float* __restrict__ theta) {
    int gid = blockIdx.x * 256 + threadIdx.x;  // 128 * 1024 * 16
    if (gid >= 128 * 1024 * 16) return;
    int bh = gid >> 14;
    int r = gid & 16383;
    int s = r >> 4, d = r & 15;
    int h = bh & 15;
    float th = theta[(s * 16 + h) * 16 + d];
    float sn, cs;
    __sincosf(th, &sn, &cs);
    size_t base = (size_t)bh * 65536 + (size_t)s * 64;
    {
        float x1 = b2f(q[base + d]), x2 = b2f(q[base + d + 16]);
        q[base + d] = f2b(x1 * cs - x2 * sn);
        q[base + d + 16] = f2b(x2 * cs + x1 * sn);
    }
    {
        float x1 = b2f(k[base + d]), x2 = b2f(k[base + d + 16]);
        k[base + d] = f2b(x1 * cs - x2 * sn);
        k[base + d + 16] = f2b(x2 * cs + x1 * sn);
    }
}

// ---------------- Flash attention (causal), q/k/v (B,H,S,D) bf16, o (B,S,H*D) bf16 ----
__launch_bounds__(256, 3) __global__
    void attn_kernel(const unsigned short* __restrict__ q, const unsigned short* __restrict__ k,
                     const unsigned short* __restrict__ v, unsigned short* __restrict__ o) {
    constexpr int S = 1024, D = 64;
    __shared__ unsigned short Ks[64][72];
    __shared__ unsigned short Vt[64][72];      // Vt[d][t]
    __shared__ unsigned short Ps[4][16][72];   // per-wave P
    const int tid = threadIdx.x, lane = tid & 63, w = tid >> 6;
    const int lr = lane & 15, lg = lane >> 4;
    const int qb = blockIdx.x;   // 0..15
    const int bh = blockIdx.y;   // 0..127
    const int qs = qb * 64;
    const size_t base = (size_t)bh * S * D;

    short8 qf[2];
    {
        const unsigned short* qp = q + base + (size_t)(qs + w * 16 + lr) * D;
        qf[0] = *(const short8*)(qp + lg * 8);
        qf[1] = *(const short8*)(qp + 32 + lg * 8);
    }

    f32x4 of[4] = {};
    float mrun[4], lrun[4];
#pragma unroll
    for (int j = 0; j < 4; ++j) {
        mrun[j] = -1e30f;
        lrun[j] = 0.f;
    }

    const int nkt = qb + 1;
    for (int kt = 0; kt < nkt; ++kt) {
        __syncthreads();
#pragma unroll
        for (int i = 0; i < 2; ++i) {
            int seg = i * 256 + tid;
            int row = seg >> 3, c8 = seg & 7;
            short8 kk = *(const short8*)(k + base + (size_t)(kt * 64 + row) * D + c8 * 8);
            *(short8*)&Ks[row][c8 * 8] = kk;
            short8 vv = *(const short8*)(v + base + (size_t)(kt * 64 + row) * D + c8 * 8);
#pragma unroll
            for (int e = 0; e < 8; ++e) Vt[c8 * 8 + e][row] = (unsigned short)vv[e];
        }
        __syncthreads();

        // QK^T (q pre-scaled by 1/8)
        f32x4 sf[4] = {};
#pragma unroll
        for (int n = 0; n < 4; ++n) {
#pragma unroll
            for (int kkc = 0; kkc < 2; ++kkc) {
                short8 bf = *(const short8*)&Ks[n * 16 + lr][kkc * 32 + lg * 8];
                sf[n] = MFMA16(qf[kkc], bf, sf[n]);
            }
        }

        if (kt == qb) {
#pragma unroll
            for (int n = 0; n < 4; ++n)
#pragma unroll
                for (int j = 0; j < 4; ++j) {
                    int qr = w * 16 + lg * 4 + j;
                    int t = n * 16 + lr;
                    if (t > qr) sf[n][j] = -1e30f;
                }
        }

        // online softmax
#pragma unroll
        for (int j = 0; j < 4; ++j) {
            float mx = fmaxf(fmaxf(sf[0][j], sf[1][j]), fmaxf(sf[2][j], sf[3][j]));
            mx = fmaxf(mx, __shfl_xor(mx, 1));
            mx = fmaxf(mx, __shfl_xor(mx, 2));
            mx = fmaxf(mx, __shfl_xor(mx, 4));
            mx = fmaxf(mx, __shfl_xor(mx, 8));
            float newm = fmaxf(mrun[j], mx);
            float sc = __expf(mrun[j] - newm);
            mrun[j] = newm;
            float psum = 0.f;
#pragma unroll
            for (int n = 0; n < 4; ++n) {
                float p = __expf(sf[n][j] - newm);
                sf[n][j] = p;
                psum += p;
            }
            lrun[j] = lrun[j] * sc + psum;
#pragma unroll
            for (int n2 = 0; n2 < 4; ++n2) of[n2][j] *= sc;
        }

        // P -> LDS (per-wave, bf16)
#pragma unroll
        for (int n = 0; n < 4; ++n)
#pragma unroll
            for (int j = 0; j < 4; ++j) Ps[w][lg * 4 + j][n * 16 + lr] = f2b(sf[n][j]);

        // PV
#pragma unroll
        for (int kkc = 0; kkc < 2; ++kkc) {
            short8 pa = *(const short8*)&Ps[w][lr][kkc * 32 + lg * 8];
#pragma unroll
            for (int n2 = 0; n2 < 4; ++n2) {
                short8 bv = *(const short8*)&Vt[n2 * 16 + lr][kkc * 32 + lg * 8];
                of[n2] = MFMA16(pa, bv, of[n2]);
            }
        }
    }

#pragma unroll
    for (int j = 0; j < 4; ++j) {
        float l = lrun[j];
        l += __shfl_xor(l, 1);
        l += __shfl_xor(l, 2);
        l += __shfl_xor(l, 4);
        l += __shfl_xor(l, 8);
        float inv = 1.f / l;
        int srow = qs + w * 16 + lg * 4 + j;
        int b = bh >> 4, h = bh & 15;
        size_t ob = ((size_t)(b * 1024 + srow)) * 1024 + h * 64;
#pragma unroll
        for (int n2 = 0; n2 < 4; ++n2) o[ob + n2 * 16 + lr] = f2b(of[n2][j] * inv);
    }
}

extern "C" void kernel_launch(void* const* d_in, const int* in_sizes, int n_in, void* d_out,
                              int out_size, void* d_ws, size_t ws_size, hipStream_t stream) {
    const float* x = (const float*)d_in[0];
    const float* scale = (const float*)d_in[1];
    const float* w_qkv = (const float*)d_in[2];
    const float* w_out = (const float*)d_in[3];
    const float* theta = (const float*)d_in[4];
    float* out = (float*)d_out;

    char* p = (char*)d_ws;
    unsigned short* xn = (unsigned short*)p;      p += (size_t)8192 * 1024 * 2;
    unsigned short* wqb = (unsigned short*)p;     p += (size_t)3072 * 1024 * 2;
    unsigned short* wob = (unsigned short*)p;     p += (size_t)1024 * 1024 * 2;
    unsigned short* qb_ = (unsigned short*)p;     p += (size_t)128 * 1024 * 64 * 2;
    unsigned short* kb_ = (unsigned short*)p;     p += (size_t)128 * 1024 * 64 * 2;
    unsigned short* vb_ = (unsigned short*)p;     p += (size_t)128 * 1024 * 64 * 2;
    unsigned short* ob_ = (unsigned short*)p;     p += (size_t)8192 * 1024 * 2;

    rmsnorm_kernel<<<8192, 256, 0, stream>>>(x, scale, xn);
    f2b_kernel<<<3072, 256, 0, stream>>>(w_qkv, wqb, 786432);
    f2b_kernel<<<1024, 256, 0, stream>>>(w_out, wob, 262144);
    gemm_bt<0><<<dim3(24, 64), 256, 0, stream>>>(xn, wqb, qb_, kb_, vb_, nullptr, nullptr);
    rope_kernel<<<8192, 256, 0, stream>>>(qb_, kb_, theta);
    attn_kernel<<<dim3(16, 128), 256, 0, stream>>>(qb_, kb_, vb_, ob_);
    gemm_bt<1><<<dim3(8, 64), 256, 0, stream>>>(ob_, wob, nullptr, nullptr, nullptr, x, out);
}

// Round 2
// 262.560 us; speedup vs baseline: 1.1385x; 1.1385x over previous
//
#include <hip/hip_runtime.h>
#include <hip/hip_bf16.h>
#include <cstdint>

typedef short short8 __attribute__((ext_vector_type(8)));
typedef float f32x4 __attribute__((ext_vector_type(4)));

#define MFMA16(a, b, c) __builtin_amdgcn_mfma_f32_16x16x32_bf16((a), (b), (c), 0, 0, 0)

__device__ __forceinline__ float b2f(unsigned short u) {
    unsigned x = ((unsigned)u) << 16;
    return __builtin_bit_cast(float, x);
}
__device__ __forceinline__ unsigned short f2b(float f) {
    unsigned x = __builtin_bit_cast(unsigned, f);
    unsigned r = (x + 0x7fffu + ((x >> 16) & 1u)) >> 16;
    return (unsigned short)r;
}

__device__ __forceinline__ void gl_lds16(const void* g, void* l) {
    __builtin_amdgcn_global_load_lds((const __attribute__((address_space(1))) void*)g,
                                     (__attribute__((address_space(3))) void*)l, 16, 0, 0);
}

// ---------------- RMSNorm: fp32 x -> bf16 xn ----------------
__global__ void rmsnorm_kernel(const float* __restrict__ x, const float* __restrict__ scale,
                               unsigned short* __restrict__ xn) {
    const int row = blockIdx.x;
    const int tid = threadIdx.x;
    const float4* xr = (const float4*)(x + (size_t)row * 1024);
    float4 vx = xr[tid];
    float ss = vx.x * vx.x + vx.y * vx.y + vx.z * vx.z + vx.w * vx.w;
#pragma unroll
    for (int m = 1; m < 64; m <<= 1) ss += __shfl_xor(ss, m);
    __shared__ float wsum[4];
    if ((tid & 63) == 0) wsum[tid >> 6] = ss;
    __syncthreads();
    float tot = wsum[0] + wsum[1] + wsum[2] + wsum[3];
    float rs = rsqrtf(tot * (1.0f / 1024.0f) + 1e-6f);
    const float4* sr = (const float4*)scale;
    float4 sv = sr[tid];
    ushort4 r;
    r.x = f2b(vx.x * sv.x * rs);
    r.y = f2b(vx.y * sv.y * rs);
    r.z = f2b(vx.z * sv.z * rs);
    r.w = f2b(vx.w * sv.w * rs);
    *(ushort4*)(xn + (size_t)row * 1024 + tid * 4) = r;
}

// ---------------- f32 -> bf16 convert ----------------
__global__ void f2b_kernel(const float* __restrict__ in, unsigned short* __restrict__ outp, int n4) {
    int i = blockIdx.x * 256 + threadIdx.x;
    if (i < n4) {
        float4 vv = ((const float4*)in)[i];
        ushort4 r;
        r.x = f2b(vv.x);
        r.y = f2b(vv.y);
        r.z = f2b(vv.z);
        r.w = f2b(vv.w);
        ((ushort4*)outp)[i] = r;
    }
}

// ---------------- GEMM C = A * B^T (A: MxK bf16 row-major, B: NxK bf16 row-major) ----
// EPI 0: scatter qkv -> q,k,v (B,H,S,D) bf16, q scaled by 0.125
// EPI 1: out[m][n] = acc + skip[m][n]  (fp32)
constexpr int BM = 128, BN = 128, BK = 64, KDIM = 1024, NT = KDIM / BK;

template <int EPI>
__launch_bounds__(256, 2) __global__
    void gemm_bt(const unsigned short* __restrict__ A, const unsigned short* __restrict__ Bw,
                 unsigned short* __restrict__ qo, unsigned short* __restrict__ ko,
                 unsigned short* __restrict__ vo, const float* __restrict__ skip,
                 float* __restrict__ out) {
    __shared__ unsigned short As[2][BM * BK];
    __shared__ unsigned short Bs[2][BN * BK];
    const int tid = threadIdx.x;
    const int lane = tid & 63, w = tid >> 6;
    const int wr = w >> 1, wc = w & 1;
    const int lr = lane & 15, lg = lane >> 4;
    // XCD-aware bijective swizzle: each XCD gets 8 consecutive by-rows.
    constexpr int NBX = (EPI == 0) ? 24 : 8;
    const int f = blockIdx.x;
    const int xcd = f & 7, wloc = f >> 3;
    const int g = xcd * (NBX * 8) + wloc;
    const int bx = g % NBX, by = g / NBX;
    const int m0 = by * BM;
    const int n0 = bx * BN;
    const int NCOL = (EPI == 0) ? 3072 : 1024;

    f32x4 acc[4][4] = {};

    auto stage = [&](int buf, int kt) {
        const int k0 = kt * BK;
#pragma unroll
        for (int i = 0; i < 4; ++i) {
            int seg = i * 256 + tid;
            int row = seg >> 3, c8 = seg & 7;
            gl_lds16(A + (size_t)(m0 + row) * KDIM + k0 + c8 * 8,
                     &As[buf][(i * 256 + w * 64) * 8]);
            gl_lds16(Bw + (size_t)(n0 + row) * KDIM + k0 + c8 * 8,
                     &Bs[buf][(i * 256 + w * 64) * 8]);
        }
    };

    stage(0, 0);
    __syncthreads();
    int cur = 0;
    for (int kt = 0; kt < NT; ++kt) {
        if (kt + 1 < NT) stage(cur ^ 1, kt + 1);
#pragma unroll
        for (int kkc = 0; kkc < 2; ++kkc) {
            short8 a[4], b[4];
#pragma unroll
            for (int m = 0; m < 4; ++m)
                a[m] = *(const short8*)&As[cur][(wr * 64 + m * 16 + lr) * BK + kkc * 32 + lg * 8];
#pragma unroll
            for (int n = 0; n < 4; ++n)
                b[n] = *(const short8*)&Bs[cur][(wc * 64 + n * 16 + lr) * BK + kkc * 32 + lg * 8];
#pragma unroll
            for (int m = 0; m < 4; ++m)
#pragma unroll
                for (int n = 0; n < 4; ++n) acc[m][n] = MFMA16(a[m], b[n], acc[m][n]);
        }
        __syncthreads();
        cur ^= 1;
    }

    if (EPI == 0) {
#pragma unroll
        for (int m = 0; m < 4; ++m)
#pragma unroll
            for (int n = 0; n < 4; ++n) {
                int gcol = n0 + wc * 64 + n * 16 + lr;
                int c = gcol >> 10, h = (gcol >> 6) & 15, d = gcol & 63;
                unsigned short* dst = (c == 0) ? qo : ((c == 1) ? ko : vo);
                float sc = (c == 0) ? 0.125f : 1.0f;
#pragma unroll
                for (int j = 0; j < 4; ++j) {
                    int grow = m0 + wr * 64 + m * 16 + lg * 4 + j;
                    int b = grow >> 10, s = grow & 1023;
                    dst[(((size_t)(b * 16 + h)) * 1024 + s) * 64 + d] = f2b(acc[m][n][j] * sc);
                }
            }
    } else {
#pragma unroll
        for (int m = 0; m < 4; ++m)
#pragma unroll
            for (int n = 0; n < 4; ++n) {
                int gcol = n0 + wc * 64 + n * 16 + lr;
#pragma unroll
                for (int j = 0; j < 4; ++j) {
                    int grow = m0 + wr * 64 + m * 16 + lg * 4 + j;
                    size_t idx = (size_t)grow * NCOL + gcol;
                    out[idx] = acc[m][n][j] + skip[idx];
                }
            }
    }
}

// ---------------- RoPE (in-place on q and k, bf16, layout (B,H,S,D)), vectorized ----
__global__ void rope_kernel(unsigned short* __restrict__ q, unsigned short* __restrict__ k,
                            const float* __restrict__ theta) {
    int gid = blockIdx.x * 256 + threadIdx.x;  // 128 * 1024 * 2
    int bh = gid >> 11;
    int r = gid & 2047;
    int s = r >> 1, half = r & 1;
    int h = bh & 15;
    int d0 = half * 8;
    size_t base = (size_t)bh * 65536 + (size_t)s * 64 + d0;
    const float* thp = theta + ((size_t)s * 16 + h) * 16 + d0;
    float4 t0 = *(const float4*)thp;
    float4 t1 = *(const float4*)(thp + 4);
    float th[8] = {t0.x, t0.y, t0.z, t0.w, t1.x, t1.y, t1.z, t1.w};
    float sn[8], cs[8];
#pragma unroll
    for (int j = 0; j < 8; ++j) __sincosf(th[j], &sn[j], &cs[j]);
#pragma unroll
    for (int t = 0; t < 2; ++t) {
        unsigned short* p = (t == 0) ? q : k;
        short8 x1 = *(short8*)(p + base);
        short8 x2 = *(short8*)(p + base + 16);
        short8 y1, y2;
#pragma unroll
        for (int j = 0; j < 8; ++j) {
            float a = b2f((unsigned short)x1[j]), b = b2f((unsigned short)x2[j]);
            y1[j] = (short)f2b(a * cs[j] - b * sn[j]);
            y2[j] = (short)f2b(b * cs[j] + a * sn[j]);
        }
        *(short8*)(p + base) = y1;
        *(short8*)(p + base + 16) = y2;
    }
}

// ---------------- Flash attention (causal), q/k/v (B,H,S,D) bf16, o (B,S,H*D) bf16 ----
// Double-buffered K (global_load_lds, source-swizzled) / V (reg-staged, rotated
// transposed stores). One barrier per kt iteration. XCD-locality block swizzle.
__launch_bounds__(256, 3) __global__
    void attn_kernel(const unsigned short* __restrict__ q, const unsigned short* __restrict__ k,
                     const unsigned short* __restrict__ v, unsigned short* __restrict__ o) {
    constexpr int S = 1024, D = 64;
    __shared__ unsigned short Ks[2][64 * 64];  // swizzled: chunk (row, c8^ (row&7))
    __shared__ unsigned short Vt[2][64][72];   // Vt[d][t]
    __shared__ unsigned short Ps[4][16][72];   // per-wave P
    const int tid = threadIdx.x, lane = tid & 63, w = tid >> 6;
    const int lr = lane & 15, lg = lane >> 4;
    // bijective: all 16 qb-tiles of a bh on one XCD, qb descending (heavy first)
    const int f = blockIdx.x;
    const int xcd = f & 7, slot = f >> 3;
    const int bh = xcd * 16 + (slot >> 4);
    const int qb = 15 - (slot & 15);
    const int qs = qb * 64;
    const size_t base = (size_t)bh * (S * D);

    short8 qf[2];
    {
        const unsigned short* qp = q + base + (size_t)(qs + w * 16 + lr) * D;
        qf[0] = *(const short8*)(qp + lg * 8);
        qf[1] = *(const short8*)(qp + 32 + lg * 8);
    }

    f32x4 of[4] = {};
    float mrun[4], lrun[4];
#pragma unroll
    for (int j = 0; j < 4; ++j) {
        mrun[j] = -1e30f;
        lrun[j] = 0.f;
    }

    const int nkt = qb + 1;
    short8 vreg[2];

    auto stageK = [&](int buf, int kt) {
#pragma unroll
        for (int i = 0; i < 2; ++i) {
            int seg = i * 256 + tid;
            int row = seg >> 3, c8 = (seg & 7) ^ (row & 7);
            gl_lds16(k + base + (size_t)(kt * 64 + row) * D + c8 * 8,
                     &Ks[buf][(i * 256 + w * 64) * 8]);
        }
    };
    auto loadV = [&](int kt) {
#pragma unroll
        for (int i = 0; i < 2; ++i) {
            int seg = i * 256 + tid;
            int row = seg >> 3, c8 = seg & 7;
            vreg[i] = *(const short8*)(v + base + (size_t)(kt * 64 + row) * D + c8 * 8);
        }
    };
    auto writeV = [&](int buf) {
#pragma unroll
        for (int i = 0; i < 2; ++i) {
            int seg = i * 256 + tid;
            int row = seg >> 3, c8 = seg & 7;
#pragma unroll
            for (int mm = 0; mm < 8; ++mm) {
                int e = (mm + c8) & 7;  // rotated order: conflict-free banks
                Vt[buf][c8 * 8 + e][row] = (unsigned short)vreg[i][e];
            }
        }
    };

    stageK(0, 0);
    loadV(0);
    writeV(0);
    __syncthreads();

    for (int kt = 0; kt < nkt; ++kt) {
        const int b = kt & 1;
        if (kt + 1 < nkt) {
            stageK(b ^ 1, kt + 1);
            loadV(kt + 1);
        }

        // QK^T (q pre-scaled by 1/8); swizzled Ks reads
        f32x4 sf[4] = {};
#pragma unroll
        for (int n = 0; n < 4; ++n) {
            const int r = n * 16 + lr;
#pragma unroll
            for (int kkc = 0; kkc < 2; ++kkc) {
                short8 bf = *(const short8*)&Ks[b][r * 64 + (((kkc * 4 + lg) ^ (lr & 7)) * 8)];
                sf[n] = MFMA16(qf[kkc], bf, sf[n]);
            }
        }

        if (kt == qb) {
#pragma unroll
            for (int n = 0; n < 4; ++n)
#pragma unroll
                for (int j = 0; j < 4; ++j) {
                    int qr = w * 16 + lg * 4 + j;
                    int t = n * 16 + lr;
                    if (t > qr) sf[n][j] = -1e30f;
                }
        }

        // online softmax
#pragma unroll
        for (int j = 0; j < 4; ++j) {
            float mx = fmaxf(fmaxf(sf[0][j], sf[1][j]), fmaxf(sf[2][j], sf[3][j]));
            mx = fmaxf(mx, __shfl_xor(mx, 1));
            mx = fmaxf(mx, __shfl_xor(mx, 2));
            mx = fmaxf(mx, __shfl_xor(mx, 4));
            mx = fmaxf(mx, __shfl_xor(mx, 8));
            float newm = fmaxf(mrun[j], mx);
            float sc = __expf(mrun[j] - newm);
            mrun[j] = newm;
            float psum = 0.f;
#pragma unroll
            for (int n = 0; n < 4; ++n) {
                float p = __expf(sf[n][j] - newm);
                sf[n][j] = p;
                psum += p;
            }
            lrun[j] = lrun[j] * sc + psum;
#pragma unroll
            for (int n2 = 0; n2 < 4; ++n2) of[n2][j] *= sc;
        }

        // P -> LDS (per-wave, bf16)
#pragma unroll
        for (int n = 0; n < 4; ++n)
#pragma unroll
            for (int j = 0; j < 4; ++j) Ps[w][lg * 4 + j][n * 16 + lr] = f2b(sf[n][j]);

        // PV
#pragma unroll
        for (int kkc = 0; kkc < 2; ++kkc) {
            short8 pa = *(const short8*)&Ps[w][lr][kkc * 32 + lg * 8];
#pragma unroll
            for (int n2 = 0; n2 < 4; ++n2) {
                short8 bv = *(const short8*)&Vt[b][n2 * 16 + lr][kkc * 32 + lg * 8];
                of[n2] = MFMA16(pa, bv, of[n2]);
            }
        }

        if (kt + 1 < nkt) writeV(b ^ 1);
        __syncthreads();
    }

#pragma unroll
    for (int j = 0; j < 4; ++j) {
        float l = lrun[j];
        l += __shfl_xor(l, 1);
        l += __shfl_xor(l, 2);
        l += __shfl_xor(l, 4);
        l += __shfl_xor(l, 8);
        float inv = 1.f / l;
        int srow = qs + w * 16 + lg * 4 + j;
        int b = bh >> 4, h = bh & 15;
        size_t ob = ((size_t)(b * 1024 + srow)) * 1024 + h * 64;
#pragma unroll
        for (int n2 = 0; n2 < 4; ++n2) o[ob + n2 * 16 + lr] = f2b(of[n2][j] * inv);
    }
}

extern "C" void kernel_launch(void* const* d_in, const int* in_sizes, int n_in, void* d_out,
                              int out_size, void* d_ws, size_t ws_size, hipStream_t stream) {
    const float* x = (const float*)d_in[0];
    const float* scale = (const float*)d_in[1];
    const float* w_qkv = (const float*)d_in[2];
    const float* w_out = (const float*)d_in[3];
    const float* theta = (const float*)d_in[4];
    float* out = (float*)d_out;

    char* p = (char*)d_ws;
    unsigned short* xn = (unsigned short*)p;      p += (size_t)8192 * 1024 * 2;
    unsigned short* wqb = (unsigned short*)p;     p += (size_t)3072 * 1024 * 2;
    unsigned short* wob = (unsigned short*)p;     p += (size_t)1024 * 1024 * 2;
    unsigned short* qb_ = (unsigned short*)p;     p += (size_t)128 * 1024 * 64 * 2;
    unsigned short* kb_ = (unsigned short*)p;     p += (size_t)128 * 1024 * 64 * 2;
    unsigned short* vb_ = (unsigned short*)p;     p += (size_t)128 * 1024 * 64 * 2;
    unsigned short* ob_ = (unsigned short*)p;     p += (size_t)8192 * 1024 * 2;

    rmsnorm_kernel<<<8192, 256, 0, stream>>>(x, scale, xn);
    f2b_kernel<<<3072, 256, 0, stream>>>(w_qkv, wqb, 786432);
    f2b_kernel<<<1024, 256, 0, stream>>>(w_out, wob, 262144);
    gemm_bt<0><<<1536, 256, 0, stream>>>(xn, wqb, qb_, kb_, vb_, nullptr, nullptr);
    rope_kernel<<<1024, 256, 0, stream>>>(qb_, kb_, theta);
    attn_kernel<<<2048, 256, 0, stream>>>(qb_, kb_, vb_, ob_);
    gemm_bt<1><<<512, 256, 0, stream>>>(ob_, wob, nullptr, nullptr, nullptr, x, out);
}